// Round 7
// baseline (93.895 us; speedup 1.0000x reference)
//
#include <hip/hip_runtime.h>
#include <math.h>

#define NSTEP 69
#define OBS 8

namespace {

constexpr float kDT = 60.0f / 69.0f;

struct ETab { float lo[NSTEP]; float mid[NSTEP]; float hi[NSTEP]; };

constexpr float interp_e(float t) {
    constexpr float DTm[16] = {0.f,2.f,4.f,6.f,8.f,10.f,12.f,14.f,16.f,18.f,20.f,25.f,30.f,40.f,50.f,60.f};
    constexpr float EP[16]  = {0.01713f,0.145f,0.2442f,0.7659f,1.0f,0.8605f,0.7829f,0.5705f,
                               0.6217f,0.331f,0.3388f,0.3116f,0.05062f,0.02504f,0.01163f,0.01163f};
    if (t >= 60.0f) return EP[15];
    if (t <= 0.0f)  return EP[0];
    int k = 0;
    for (int m = 0; m < 15; m++) if (t >= DTm[m]) k = m;
    float u = (t - DTm[k]) / (DTm[k + 1] - DTm[k]);
    return EP[k] + u * (EP[k + 1] - EP[k]);
}

constexpr ETab make_etab() {
    ETab e{};
    for (int s = 0; s < NSTEP; s++) {
        float t0 = (float)s * kDT;
        e.lo[s]  = interp_e(t0);
        e.mid[s] = interp_e(t0 + 0.5f * kDT);
        e.hi[s]  = interp_e(t0 + kDT);
    }
    return e;
}

} // namespace

__device__ constexpr ETab ETAB = make_etab();

// Lane-pair split: element e on lanes (2m, 2m+1).
// Both lanes replicate specials x0,x1,x2 (identical math).
// lane0 chain c0..c3 = q1..q4 (head prev = local x2)
// lane1 chain c0..c3 = q5..q7,out (head prev = partner's q4)
// Per deriv stage: ONE shfl_xor of the chain tail gives lane0 the partner's
// `out` (for d0 feedback) and lane1 the partner's `q4` (chain head).
struct St7 { float x0, x1, x2, c0, c1, c2, c3; };
struct Dv7 { float d0, d1, d2, e0, e1, e2, e3; };

__device__ __forceinline__ Dv7 deriv(const St7& s, float k1E, float k2, float r, bool hi) {
    float tp = __shfl_xor(s.c3, 1, 64);     // partner's tail
    float hp = hi ? tp   : s.x2;            // chain-head prev
    float ov = hi ? s.c3 : tp;              // `out` for d0 feedback
    float a  = k1E * s.x0;
    float sq = s.x1 * s.x1;
    Dv7 d;
    d.d0 = fmaf(k2, ov, -a);
    d.d1 = a - sq;
    d.d2 = fmaf(-k2, s.x2, sq);
    d.e0 = r * (hp   - s.c0);
    d.e1 = r * (s.c0 - s.c1);
    d.e2 = r * (s.c1 - s.c2);
    d.e3 = r * (s.c2 - s.c3);
    return d;
}

__device__ __forceinline__ St7 axpy(const St7& x, float c, const Dv7& d) {
    St7 y;
    y.x0 = fmaf(c, d.d0, x.x0);
    y.x1 = fmaf(c, d.d1, x.x1);
    y.x2 = fmaf(c, d.d2, x.x2);
    y.c0 = fmaf(c, d.e0, x.c0);
    y.c1 = fmaf(c, d.e1, x.c1);
    y.c2 = fmaf(c, d.e2, x.c2);
    y.c3 = fmaf(c, d.e3, x.c3);
    return y;
}

__global__ __launch_bounds__(256) void stats5_kernel(
    const float* __restrict__ params,
    const float* __restrict__ design,
    const float* __restrict__ noise,
    float* __restrict__ out,
    int B)
{
    int t = blockIdx.x * blockDim.x + threadIdx.x;
    int e = t >> 1;
    if (e >= B) return;
    const bool hi = (t & 1);

    // ---- design readout (wave-uniform -> SGPR)
    int ij[OBS], ij1[OBS]; float wj[OBS], w1j[OBS];
    #pragma unroll
    for (int j = 0; j < OBS; j++) {
        float pos = design[j] * (1.0f / kDT);
        int i = (int)pos;
        i = i < 0 ? 0 : (i > NSTEP - 1 ? NSTEP - 1 : i);
        float w = pos - (float)i;
        ij[j]  = __builtin_amdgcn_readfirstlane(i);
        ij1[j] = ij[j] + 1;
        int wb = __builtin_amdgcn_readfirstlane(__float_as_int(w));
        wj[j]  = __int_as_float(wb);
        w1j[j] = 1.0f - wj[j];
    }

    unsigned long long m_lo = 0ull, m_hi = 0ull;
    #pragma unroll
    for (int j = 0; j < OBS; j++) {
        if (ij[j]  < 64) m_lo |= 1ull << ij[j];  else m_hi |= 1ull << (ij[j]  - 64);
        if (ij1[j] < 64) m_lo |= 1ull << ij1[j]; else m_hi |= 1ull << (ij1[j] - 64);
    }

    // ---- parameter transform (replicated in both lanes of the pair)
    float p0 = params[3 * e], p1 = params[3 * e + 1], p2 = params[3 * e + 2];
    const float INV_SQRT2 = 0.7071067811865476f;
    float k1  = fmaf(0.5f * erfcf(-p0 * INV_SQRT2), 2.5f,  0.5f);
    float k2  = fmaf(0.5f * erfcf(-p1 * INV_SQRT2), 0.15f, 0.05f);
    float tau = fmaf(0.5f * erfcf(-p2 * INV_SQRT2), 6.0f,  4.0f);
    float r = 8.0f / tau;

    float a12[OBS], a0[OBS], b12[OBS], b0[OBS];
    #pragma unroll
    for (int j = 0; j < OBS; j++) { a12[j] = 0.f; a0[j] = 0.f; b12[j] = 0.f; b0[j] = 0.f; }

    St7 x;
    x.x0 = 3.71f; x.x1 = 0.f; x.x2 = 0.f;
    x.c0 = 0.f; x.c1 = 0.f; x.c2 = 0.f; x.c3 = 0.f;

    if (m_lo & 1ull) {
        #pragma unroll
        for (int j = 0; j < OBS; j++)
            if (ij[j] == 0) { a12[j] = 0.f; a0[j] = 3.71f; }
    }

    #pragma unroll 1
    for (int s = 0; s < NSTEP; s++) {
        float ea = ETAB.lo[s], eb = ETAB.mid[s], ec = ETAB.hi[s];
        float k1a = k1 * ea, k1b = k1 * eb, k1c = k1 * ec;

        Dv7 d1 = deriv(x, k1a, k2, r, hi);
        St7 tt = axpy(x, 0.5f * kDT, d1);
        Dv7 d2 = deriv(tt, k1b, k2, r, hi);
        tt     = axpy(x, 0.5f * kDT, d2);
        Dv7 d3 = deriv(tt, k1b, k2, r, hi);
        tt     = axpy(x, kDT, d3);
        Dv7 d4 = deriv(tt, k1c, k2, r, hi);

        const float c6 = kDT * (1.0f / 6.0f);
        {
            float u;
            u = fmaf(2.0f, d2.d0 + d3.d0, d1.d0 + d4.d0); x.x0 = fmaf(c6, u, x.x0);
            u = fmaf(2.0f, d2.d1 + d3.d1, d1.d1 + d4.d1); x.x1 = fmaf(c6, u, x.x1);
            u = fmaf(2.0f, d2.d2 + d3.d2, d1.d2 + d4.d2); x.x2 = fmaf(c6, u, x.x2);
            u = fmaf(2.0f, d2.e0 + d3.e0, d1.e0 + d4.e0); x.c0 = fmaf(c6, u, x.c0);
            u = fmaf(2.0f, d2.e1 + d3.e1, d1.e1 + d4.e1); x.c1 = fmaf(c6, u, x.c1);
            u = fmaf(2.0f, d2.e2 + d3.e2, d1.e2 + d4.e2); x.c2 = fmaf(c6, u, x.c2);
            u = fmaf(2.0f, d2.e3 + d3.e3, d1.e3 + d4.e3); x.c3 = fmaf(c6, u, x.c3);
        }

        int ti = s + 1;
        unsigned long long mm = (ti < 64) ? (m_lo >> ti) : (m_hi >> (ti - 64));
        if (__builtin_expect((int)(mm & 1ull), 0)) {
            float s12 = x.x1 + x.x2;
            #pragma unroll
            for (int j = 0; j < OBS; j++) {
                if (ti == ij[j])  { a12[j] = s12; a0[j] = x.x0; }
                if (ti == ij1[j]) { b12[j] = s12; b0[j] = x.x0; }
            }
        }
    }

    float o1[OBS], o2[OBS];
    #pragma unroll
    for (int j = 0; j < OBS; j++) {
        o1[j] = 0.33f * fmaf(w1j[j], a12[j], wj[j] * b12[j]);
        o2[j] = 0.26f * fmaf(w1j[j], a0[j] + a12[j], wj[j] * (b0[j] + b12[j]));
    }

    float4 v0 = make_float4(o1[0], o1[1], o1[2], o1[3]);
    float4 v1 = make_float4(o1[4], o1[5], o1[6], o1[7]);
    float4 v2 = make_float4(o2[0], o2[1], o2[2], o2[3]);
    float4 v3 = make_float4(o2[4], o2[5], o2[6], o2[7]);

    long long base = (long long)e * 16;
    long long nb   = (long long)B * 16;

    if (!hi) {
        // lane0: true observations
        float4* outv = (float4*)(out + base);
        outv[0] = v0; outv[1] = v1; outv[2] = v2; outv[3] = v3;
    } else {
        // lane1: noised observations
        const float4* nz = (const float4*)(noise + base);
        float4 n0 = nz[0], n1 = nz[1], n2 = nz[2], n3 = nz[3];
        float4* outn = (float4*)(out + nb + base);
        outn[0] = make_float4(fmaf(0.01f, n0.x, v0.x), fmaf(0.01f, n0.y, v0.y),
                              fmaf(0.01f, n0.z, v0.z), fmaf(0.01f, n0.w, v0.w));
        outn[1] = make_float4(fmaf(0.01f, n1.x, v1.x), fmaf(0.01f, n1.y, v1.y),
                              fmaf(0.01f, n1.z, v1.z), fmaf(0.01f, n1.w, v1.w));
        outn[2] = make_float4(fmaf(0.01f, n2.x, v2.x), fmaf(0.01f, n2.y, v2.y),
                              fmaf(0.01f, n2.z, v2.z), fmaf(0.01f, n2.w, v2.w));
        outn[3] = make_float4(fmaf(0.01f, n3.x, v3.x), fmaf(0.01f, n3.y, v3.y),
                              fmaf(0.01f, n3.z, v3.z), fmaf(0.01f, n3.w, v3.w));
    }
}

extern "C" void kernel_launch(void* const* d_in, const int* in_sizes, int n_in,
                              void* d_out, int out_size, void* d_ws, size_t ws_size,
                              hipStream_t stream) {
    const float* params = (const float*)d_in[0];
    const float* design = (const float*)d_in[1];
    const float* noise  = (const float*)d_in[2];
    float* out = (float*)d_out;
    int B = in_sizes[0] / 3;
    int threads = 2 * B;                  // lane pair per element -> 2 waves/SIMD
    int block = 256;
    int grid = (threads + block - 1) / block;
    stats5_kernel<<<grid, block, 0, stream>>>(params, design, noise, out, B);
}

// Round 8
// 90.747 us; speedup vs baseline: 1.0347x; 1.0347x over previous
//
#include <hip/hip_runtime.h>
#include <math.h>

#define NSTEP 69
#define OBS 8

namespace {

constexpr float kDT = 60.0f / 69.0f;

struct ETab { float lo[NSTEP]; float mid[NSTEP]; float hi[NSTEP]; };

constexpr float interp_e(float t) {
    constexpr float DTm[16] = {0.f,2.f,4.f,6.f,8.f,10.f,12.f,14.f,16.f,18.f,20.f,25.f,30.f,40.f,50.f,60.f};
    constexpr float EP[16]  = {0.01713f,0.145f,0.2442f,0.7659f,1.0f,0.8605f,0.7829f,0.5705f,
                               0.6217f,0.331f,0.3388f,0.3116f,0.05062f,0.02504f,0.01163f,0.01163f};
    if (t >= 60.0f) return EP[15];
    if (t <= 0.0f)  return EP[0];
    int k = 0;
    for (int m = 0; m < 15; m++) if (t >= DTm[m]) k = m;
    float u = (t - DTm[k]) / (DTm[k + 1] - DTm[k]);
    return EP[k] + u * (EP[k + 1] - EP[k]);
}

constexpr ETab make_etab() {
    ETab e{};
    for (int s = 0; s < NSTEP; s++) {
        float t0 = (float)s * kDT;
        e.lo[s]  = interp_e(t0);
        e.mid[s] = interp_e(t0 + 0.5f * kDT);
        e.hi[s]  = interp_e(t0 + kDT);
    }
    return e;
}

} // namespace

__device__ constexpr ETab ETAB = make_etab();

// DPP quad_perm [1,0,3,2]: swap adjacent lanes (2m <-> 2m+1). Pure VALU mov,
// no LDS crossbar / lgkmcnt — this replaces R7's ds_permute shfl.
__device__ __forceinline__ float dpp_swap1(float v) {
    int i = __float_as_int(v);
    return __int_as_float(__builtin_amdgcn_update_dpp(i, i, 0xB1, 0xF, 0xF, false));
}

// Lane-pair split of one element over lanes (2m, 2m+1):
//   both lanes replicate specials x0,x1,x2 (identical math, no comms)
//   lane-lo chain (w-space, w=r*q): w0..w3 = r*(q1..q4), head prev = r*x2
//   lane-hi chain:                  w0..w3 = r*(q5..q7,out), head prev = lo's w3
// Per deriv stage the ONLY exchange is w3 (tail): one DPP swap.
//   ov (out-feedback, w-units) = hi ? local w3 : swapped
//   hp (chain-head prev)       = hi ? swapped  : r*x2

__global__ __launch_bounds__(256) void stats5_kernel(
    const float* __restrict__ params,
    const float* __restrict__ design,
    const float* __restrict__ noise,
    float* __restrict__ out,
    int B)
{
    int t = blockIdx.x * blockDim.x + threadIdx.x;
    int e = t >> 1;
    if (e >= B) return;
    const bool hi = (t & 1);

    // ---- design readout (wave-uniform -> SGPR)
    int ij[OBS], ij1[OBS]; float wj[OBS], w1j[OBS];
    #pragma unroll
    for (int j = 0; j < OBS; j++) {
        float pos = design[j] * (1.0f / kDT);
        int i = (int)pos;
        i = i < 0 ? 0 : (i > NSTEP - 1 ? NSTEP - 1 : i);
        float w = pos - (float)i;
        ij[j]  = __builtin_amdgcn_readfirstlane(i);
        ij1[j] = ij[j] + 1;
        int wb = __builtin_amdgcn_readfirstlane(__float_as_int(w));
        wj[j]  = __int_as_float(wb);
        w1j[j] = 1.0f - wj[j];
    }

    unsigned long long m_lo = 0ull, m_hi = 0ull;
    #pragma unroll
    for (int j = 0; j < OBS; j++) {
        if (ij[j]  < 64) m_lo |= 1ull << ij[j];  else m_hi |= 1ull << (ij[j]  - 64);
        if (ij1[j] < 64) m_lo |= 1ull << ij1[j]; else m_hi |= 1ull << (ij1[j] - 64);
    }

    // ---- parameter transform (replicated across the lane pair)
    float p0 = params[3 * e], p1 = params[3 * e + 1], p2 = params[3 * e + 2];
    const float INV_SQRT2 = 0.7071067811865476f;
    float k1  = fmaf(0.5f * erfcf(-p0 * INV_SQRT2), 2.5f,  0.5f);
    float k2  = fmaf(0.5f * erfcf(-p1 * INV_SQRT2), 0.15f, 0.05f);
    float tau = fmaf(0.5f * erfcf(-p2 * INV_SQRT2), 6.0f,  4.0f);
    float r   = 8.0f / tau;

    // loop-invariant stage constants (w-space chain)
    const float hdt  = 0.5f * kDT;
    const float c6   = kDT * (1.0f / 6.0f);
    const float cr_h = hdt * r;
    const float cr_f = kDT * r;
    const float c6r  = c6 * r;
    const float k2r  = 0.125f * k2 * tau;   // k2 / r, no division

    float a12[OBS], a0[OBS], b12[OBS], b0[OBS];
    #pragma unroll
    for (int j = 0; j < OBS; j++) { a12[j] = 0.f; a0[j] = 0.f; b12[j] = 0.f; b0[j] = 0.f; }

    float x0 = 3.71f, x1 = 0.f, x2 = 0.f;
    float w0 = 0.f, w1 = 0.f, w2 = 0.f, w3 = 0.f;

    if (m_lo & 1ull) {
        #pragma unroll
        for (int j = 0; j < OBS; j++)
            if (ij[j] == 0) { a12[j] = 0.f; a0[j] = 3.71f; }
    }

    auto DERIV = [&](float k1E, float X0, float X1, float X2,
                     float W0, float W1, float W2, float W3,
                     float& D0, float& D1, float& D2,
                     float& G0, float& G1, float& G2, float& G3) {
        float sw = dpp_swap1(W3);
        float ov = hi ? W3 : sw;        // w_out (w-units)
        float hp = hi ? sw : r * X2;    // chain-head prev (w-units)
        float a  = k1E * X0;
        float sq = X1 * X1;
        D0 = fmaf(k2r, ov, -a);
        D1 = a - sq;
        D2 = fmaf(-k2, X2, sq);
        G0 = hp - W0;
        G1 = W0 - W1;
        G2 = W1 - W2;
        G3 = W2 - W3;
    };

    #pragma unroll 1
    for (int s = 0; s < NSTEP; s++) {
        float ea = ETAB.lo[s], eb = ETAB.mid[s], ec = ETAB.hi[s];
        float k1a = k1 * ea, k1b = k1 * eb, k1c = k1 * ec;

        float d10,d11,d12,g10,g11,g12,g13;
        float d20,d21,d22,g20,g21,g22,g23;
        float d30,d31,d32,g30,g31,g32,g33;
        float d40,d41,d42,g40,g41,g42,g43;
        float t0,t1,t2,u0,u1,u2,u3;

        DERIV(k1a, x0,x1,x2, w0,w1,w2,w3, d10,d11,d12, g10,g11,g12,g13);
        t0 = fmaf(hdt, d10, x0); t1 = fmaf(hdt, d11, x1); t2 = fmaf(hdt, d12, x2);
        u0 = fmaf(cr_h, g10, w0); u1 = fmaf(cr_h, g11, w1);
        u2 = fmaf(cr_h, g12, w2); u3 = fmaf(cr_h, g13, w3);

        DERIV(k1b, t0,t1,t2, u0,u1,u2,u3, d20,d21,d22, g20,g21,g22,g23);
        t0 = fmaf(hdt, d20, x0); t1 = fmaf(hdt, d21, x1); t2 = fmaf(hdt, d22, x2);
        u0 = fmaf(cr_h, g20, w0); u1 = fmaf(cr_h, g21, w1);
        u2 = fmaf(cr_h, g22, w2); u3 = fmaf(cr_h, g23, w3);

        DERIV(k1b, t0,t1,t2, u0,u1,u2,u3, d30,d31,d32, g30,g31,g32,g33);
        t0 = fmaf(kDT, d30, x0); t1 = fmaf(kDT, d31, x1); t2 = fmaf(kDT, d32, x2);
        u0 = fmaf(cr_f, g30, w0); u1 = fmaf(cr_f, g31, w1);
        u2 = fmaf(cr_f, g32, w2); u3 = fmaf(cr_f, g33, w3);

        DERIV(k1c, t0,t1,t2, u0,u1,u2,u3, d40,d41,d42, g40,g41,g42,g43);

        float u;
        u = fmaf(2.0f, d20 + d30, d10 + d40); x0 = fmaf(c6, u, x0);
        u = fmaf(2.0f, d21 + d31, d11 + d41); x1 = fmaf(c6, u, x1);
        u = fmaf(2.0f, d22 + d32, d12 + d42); x2 = fmaf(c6, u, x2);
        u = fmaf(2.0f, g20 + g30, g10 + g40); w0 = fmaf(c6r, u, w0);
        u = fmaf(2.0f, g21 + g31, g11 + g41); w1 = fmaf(c6r, u, w1);
        u = fmaf(2.0f, g22 + g32, g12 + g42); w2 = fmaf(c6r, u, w2);
        u = fmaf(2.0f, g23 + g33, g13 + g43); w3 = fmaf(c6r, u, w3);

        int ti = s + 1;
        unsigned long long mm = (ti < 64) ? (m_lo >> ti) : (m_hi >> (ti - 64));
        if (__builtin_expect((int)(mm & 1ull), 0)) {
            float s12 = x1 + x2;
            #pragma unroll
            for (int j = 0; j < OBS; j++) {
                if (ti == ij[j])  { a12[j] = s12; a0[j] = x0; }
                if (ti == ij1[j]) { b12[j] = s12; b0[j] = x0; }
            }
        }
    }

    float o1[OBS], o2[OBS];
    #pragma unroll
    for (int j = 0; j < OBS; j++) {
        o1[j] = 0.33f * fmaf(w1j[j], a12[j], wj[j] * b12[j]);
        o2[j] = 0.26f * fmaf(w1j[j], a0[j] + a12[j], wj[j] * (b0[j] + b12[j]));
    }

    float4 v0 = make_float4(o1[0], o1[1], o1[2], o1[3]);
    float4 v1 = make_float4(o1[4], o1[5], o1[6], o1[7]);
    float4 v2 = make_float4(o2[0], o2[1], o2[2], o2[3]);
    float4 v3 = make_float4(o2[4], o2[5], o2[6], o2[7]);

    long long base = (long long)e * 16;
    long long nb   = (long long)B * 16;

    if (!hi) {
        float4* outv = (float4*)(out + base);
        outv[0] = v0; outv[1] = v1; outv[2] = v2; outv[3] = v3;
    } else {
        const float4* nz = (const float4*)(noise + base);
        float4 n0 = nz[0], n1 = nz[1], n2 = nz[2], n3 = nz[3];
        float4* outn = (float4*)(out + nb + base);
        outn[0] = make_float4(fmaf(0.01f, n0.x, v0.x), fmaf(0.01f, n0.y, v0.y),
                              fmaf(0.01f, n0.z, v0.z), fmaf(0.01f, n0.w, v0.w));
        outn[1] = make_float4(fmaf(0.01f, n1.x, v1.x), fmaf(0.01f, n1.y, v1.y),
                              fmaf(0.01f, n1.z, v1.z), fmaf(0.01f, n1.w, v1.w));
        outn[2] = make_float4(fmaf(0.01f, n2.x, v2.x), fmaf(0.01f, n2.y, v2.y),
                              fmaf(0.01f, n2.z, v2.z), fmaf(0.01f, n2.w, v2.w));
        outn[3] = make_float4(fmaf(0.01f, n3.x, v3.x), fmaf(0.01f, n3.y, v3.y),
                              fmaf(0.01f, n3.z, v3.z), fmaf(0.01f, n3.w, v3.w));
    }
}

extern "C" void kernel_launch(void* const* d_in, const int* in_sizes, int n_in,
                              void* d_out, int out_size, void* d_ws, size_t ws_size,
                              hipStream_t stream) {
    const float* params = (const float*)d_in[0];
    const float* design = (const float*)d_in[1];
    const float* noise  = (const float*)d_in[2];
    float* out = (float*)d_out;
    int B = in_sizes[0] / 3;
    int threads = 2 * B;                  // lane pair per element -> 2 waves/SIMD
    int block = 256;
    int grid = (threads + block - 1) / block;
    stats5_kernel<<<grid, block, 0, stream>>>(params, design, noise, out, B);
}

// Round 9
// 84.340 us; speedup vs baseline: 1.1133x; 1.0760x over previous
//
#include <hip/hip_runtime.h>
#include <math.h>

#define NSTEP 69
#define OBS 8

typedef float f32x2 __attribute__((ext_vector_type(2)));

namespace {

constexpr float kDT = 60.0f / 69.0f;

struct ETab { float lo[NSTEP]; float mid[NSTEP]; float hi[NSTEP]; };

constexpr float interp_e(float t) {
    constexpr float DTm[16] = {0.f,2.f,4.f,6.f,8.f,10.f,12.f,14.f,16.f,18.f,20.f,25.f,30.f,40.f,50.f,60.f};
    constexpr float EP[16]  = {0.01713f,0.145f,0.2442f,0.7659f,1.0f,0.8605f,0.7829f,0.5705f,
                               0.6217f,0.331f,0.3388f,0.3116f,0.05062f,0.02504f,0.01163f,0.01163f};
    if (t >= 60.0f) return EP[15];
    if (t <= 0.0f)  return EP[0];
    int k = 0;
    for (int m = 0; m < 15; m++) if (t >= DTm[m]) k = m;
    float u = (t - DTm[k]) / (DTm[k + 1] - DTm[k]);
    return EP[k] + u * (EP[k + 1] - EP[k]);
}

constexpr ETab make_etab() {
    ETab e{};
    for (int s = 0; s < NSTEP; s++) {
        float t0 = (float)s * kDT;
        e.lo[s]  = interp_e(t0);
        e.mid[s] = interp_e(t0 + 0.5f * kDT);
        e.hi[s]  = interp_e(t0 + kDT);
    }
    return e;
}

constexpr ETab ETAB = make_etab();   // literals under full unroll

} // namespace

// Single-lane, w-space chain (w_i = r*q_i):
//   specials x0,x1,x2 (scalar);
//   chain pairs W0=(w_q1,w_q5) W1=(w_q2,w_q6) W2=(w_q3,w_q7) W3=(w_q4,w_out)
//   prev(W0) = (r*x2, W3.x); chain derivs are PURE SUBTRACTS in w-units:
//     dW/dt = r * (W_prev - W); the r folds into stage constants cr_* and c6r.
//   out-feedback: k2*out = (k2*tau/8) * w_out = k2r * W3.y
struct Dv { float d0, d1, d2; f32x2 G0, G1, G2, G3; };

__global__ __launch_bounds__(256) void stats5_kernel(
    const float* __restrict__ params,
    const float* __restrict__ design,
    const float* __restrict__ noise,
    float* __restrict__ out,
    int B)
{
    int b = blockIdx.x * blockDim.x + threadIdx.x;
    if (b >= B) return;

    // ---- design readout (wave-uniform -> SGPR)
    int ij[OBS], ij1[OBS]; float wj[OBS], w1j[OBS];
    #pragma unroll
    for (int j = 0; j < OBS; j++) {
        float pos = design[j] * (1.0f / kDT);
        int i = (int)pos;
        i = i < 0 ? 0 : (i > NSTEP - 1 ? NSTEP - 1 : i);
        float w = pos - (float)i;
        ij[j]  = __builtin_amdgcn_readfirstlane(i);
        ij1[j] = ij[j] + 1;
        int wb = __builtin_amdgcn_readfirstlane(__float_as_int(w));
        wj[j]  = __int_as_float(wb);
        w1j[j] = 1.0f - wj[j];
    }

    unsigned long long m_lo = 0ull, m_hi = 0ull;
    #pragma unroll
    for (int j = 0; j < OBS; j++) {
        if (ij[j]  < 64) m_lo |= 1ull << ij[j];  else m_hi |= 1ull << (ij[j]  - 64);
        if (ij1[j] < 64) m_lo |= 1ull << ij1[j]; else m_hi |= 1ull << (ij1[j] - 64);
    }

    // ---- parameter transform
    float p0 = params[3 * b], p1 = params[3 * b + 1], p2 = params[3 * b + 2];
    const float INV_SQRT2 = 0.7071067811865476f;
    float k1  = fmaf(0.5f * erfcf(-p0 * INV_SQRT2), 2.5f,  0.5f);
    float k2  = fmaf(0.5f * erfcf(-p1 * INV_SQRT2), 0.15f, 0.05f);
    float tau = fmaf(0.5f * erfcf(-p2 * INV_SQRT2), 6.0f,  4.0f);
    float r   = 8.0f / tau;

    const float hdt  = 0.5f * kDT;
    const float c6   = kDT * (1.0f / 6.0f);
    const float k2r  = 0.125f * k2 * tau;          // k2 / r (no division)
    const f32x2 crh2 = {hdt * r, hdt * r};         // stage consts, w-space
    const f32x2 crf2 = {kDT * r, kDT * r};
    const f32x2 c6r2 = {c6 * r, c6 * r};

    float a12[OBS], a0[OBS], b12[OBS], b0[OBS];
    #pragma unroll
    for (int j = 0; j < OBS; j++) { a12[j] = 0.f; a0[j] = 0.f; b12[j] = 0.f; b0[j] = 0.f; }

    float x0 = 3.71f, x1 = 0.f, x2 = 0.f;
    f32x2 W0 = {0.f, 0.f}, W1 = W0, W2 = W0, W3 = W0;

    if (m_lo & 1ull) {
        #pragma unroll
        for (int j = 0; j < OBS; j++)
            if (ij[j] == 0) { a12[j] = 0.f; a0[j] = 3.71f; }
    }

    auto DERIV = [&](float k1E, float X0, float X1, float X2,
                     const f32x2& V0, const f32x2& V1, const f32x2& V2, const f32x2& V3) {
        Dv d;
        float a  = k1E * X0;
        float sq = X1 * X1;
        d.d0 = fmaf(k2r, V3.y, -a);
        d.d1 = a - sq;
        d.d2 = fmaf(-k2, X2, sq);
        f32x2 s0; s0.x = r * X2; s0.y = V3.x;
        d.G0 = s0 - V0;      // pk_add w/ neg (pure subs — w-space)
        d.G1 = V0 - V1;
        d.G2 = V1 - V2;
        d.G3 = V2 - V3;
        return d;
    };

    #pragma unroll
    for (int s = 0; s < NSTEP; s++) {
        const float ea = ETAB.lo[s], eb = ETAB.mid[s], ec = ETAB.hi[s];
        float k1a = k1 * ea, k1b = k1 * eb, k1c = k1 * ec;

        float t0, t1, t2; f32x2 U0, U1, U2, U3;

        Dv d1 = DERIV(k1a, x0, x1, x2, W0, W1, W2, W3);
        t0 = fmaf(hdt, d1.d0, x0); t1 = fmaf(hdt, d1.d1, x1); t2 = fmaf(hdt, d1.d2, x2);
        U0 = crh2 * d1.G0 + W0; U1 = crh2 * d1.G1 + W1;
        U2 = crh2 * d1.G2 + W2; U3 = crh2 * d1.G3 + W3;

        Dv d2 = DERIV(k1b, t0, t1, t2, U0, U1, U2, U3);
        t0 = fmaf(hdt, d2.d0, x0); t1 = fmaf(hdt, d2.d1, x1); t2 = fmaf(hdt, d2.d2, x2);
        U0 = crh2 * d2.G0 + W0; U1 = crh2 * d2.G1 + W1;
        U2 = crh2 * d2.G2 + W2; U3 = crh2 * d2.G3 + W3;

        Dv d3 = DERIV(k1b, t0, t1, t2, U0, U1, U2, U3);
        t0 = fmaf(kDT, d3.d0, x0); t1 = fmaf(kDT, d3.d1, x1); t2 = fmaf(kDT, d3.d2, x2);
        U0 = crf2 * d3.G0 + W0; U1 = crf2 * d3.G1 + W1;
        U2 = crf2 * d3.G2 + W2; U3 = crf2 * d3.G3 + W3;

        Dv d4 = DERIV(k1c, t0, t1, t2, U0, U1, U2, U3);

        float u;
        u = fmaf(2.0f, d2.d0 + d3.d0, d1.d0 + d4.d0); x0 = fmaf(c6, u, x0);
        u = fmaf(2.0f, d2.d1 + d3.d1, d1.d1 + d4.d1); x1 = fmaf(c6, u, x1);
        u = fmaf(2.0f, d2.d2 + d3.d2, d1.d2 + d4.d2); x2 = fmaf(c6, u, x2);
        f32x2 two = {2.0f, 2.0f}, v;
        v = two * (d2.G0 + d3.G0) + (d1.G0 + d4.G0); W0 = c6r2 * v + W0;
        v = two * (d2.G1 + d3.G1) + (d1.G1 + d4.G1); W1 = c6r2 * v + W1;
        v = two * (d2.G2 + d3.G2) + (d1.G2 + d4.G2); W2 = c6r2 * v + W2;
        v = two * (d2.G3 + d3.G3) + (d1.G3 + d4.G3); W3 = c6r2 * v + W3;

        const int ti = s + 1;
        unsigned long long mm = (ti < 64) ? (m_lo >> ti) : (m_hi >> (ti - 64));
        if (__builtin_expect((int)(mm & 1ull), 0)) {
            float s12 = x1 + x2;
            #pragma unroll
            for (int j = 0; j < OBS; j++) {
                if (ti == ij[j])  { a12[j] = s12; a0[j] = x0; }
                if (ti == ij1[j]) { b12[j] = s12; b0[j] = x0; }
            }
        }
    }

    float o1[OBS], o2[OBS];
    #pragma unroll
    for (int j = 0; j < OBS; j++) {
        o1[j] = 0.33f * fmaf(w1j[j], a12[j], wj[j] * b12[j]);
        o2[j] = 0.26f * fmaf(w1j[j], a0[j] + a12[j], wj[j] * (b0[j] + b12[j]));
    }

    long long base = (long long)b * 16;
    long long nb   = (long long)B * 16;
    float4* outv = (float4*)(out + base);
    float4* outn = (float4*)(out + nb + base);
    const float4* nz = (const float4*)(noise + base);

    float4 v0 = make_float4(o1[0], o1[1], o1[2], o1[3]);
    float4 v1 = make_float4(o1[4], o1[5], o1[6], o1[7]);
    float4 v2 = make_float4(o2[0], o2[1], o2[2], o2[3]);
    float4 v3 = make_float4(o2[4], o2[5], o2[6], o2[7]);
    outv[0] = v0; outv[1] = v1; outv[2] = v2; outv[3] = v3;

    float4 n0 = nz[0], n1 = nz[1], n2 = nz[2], n3 = nz[3];
    outn[0] = make_float4(fmaf(0.01f, n0.x, v0.x), fmaf(0.01f, n0.y, v0.y),
                          fmaf(0.01f, n0.z, v0.z), fmaf(0.01f, n0.w, v0.w));
    outn[1] = make_float4(fmaf(0.01f, n1.x, v1.x), fmaf(0.01f, n1.y, v1.y),
                          fmaf(0.01f, n1.z, v1.z), fmaf(0.01f, n1.w, v1.w));
    outn[2] = make_float4(fmaf(0.01f, n2.x, v2.x), fmaf(0.01f, n2.y, v2.y),
                          fmaf(0.01f, n2.z, v2.z), fmaf(0.01f, n2.w, v2.w));
    outn[3] = make_float4(fmaf(0.01f, n3.x, v3.x), fmaf(0.01f, n3.y, v3.y),
                          fmaf(0.01f, n3.z, v3.z), fmaf(0.01f, n3.w, v3.w));
}

extern "C" void kernel_launch(void* const* d_in, const int* in_sizes, int n_in,
                              void* d_out, int out_size, void* d_ws, size_t ws_size,
                              hipStream_t stream) {
    const float* params = (const float*)d_in[0];
    const float* design = (const float*)d_in[1];
    const float* noise  = (const float*)d_in[2];
    float* out = (float*)d_out;
    int B = in_sizes[0] / 3;
    int block = 256;
    int grid = (B + block - 1) / block;
    stats5_kernel<<<grid, block, 0, stream>>>(params, design, noise, out, B);
}

// Round 10
// 83.367 us; speedup vs baseline: 1.1263x; 1.0117x over previous
//
#include <hip/hip_runtime.h>
#include <math.h>

#define NSTEP 69
#define OBS 8

typedef float f32x2 __attribute__((ext_vector_type(2)));

namespace {

constexpr float kDT = 60.0f / 69.0f;

struct ETab { float lo[NSTEP]; float mid[NSTEP]; float hi[NSTEP]; };

constexpr float interp_e(float t) {
    constexpr float DTm[16] = {0.f,2.f,4.f,6.f,8.f,10.f,12.f,14.f,16.f,18.f,20.f,25.f,30.f,40.f,50.f,60.f};
    constexpr float EP[16]  = {0.01713f,0.145f,0.2442f,0.7659f,1.0f,0.8605f,0.7829f,0.5705f,
                               0.6217f,0.331f,0.3388f,0.3116f,0.05062f,0.02504f,0.01163f,0.01163f};
    if (t >= 60.0f) return EP[15];
    if (t <= 0.0f)  return EP[0];
    int k = 0;
    for (int m = 0; m < 15; m++) if (t >= DTm[m]) k = m;
    float u = (t - DTm[k]) / (DTm[k + 1] - DTm[k]);
    return EP[k] + u * (EP[k + 1] - EP[k]);
}

constexpr ETab make_etab() {
    ETab e{};
    for (int s = 0; s < NSTEP; s++) {
        float t0 = (float)s * kDT;
        e.lo[s]  = interp_e(t0);
        e.mid[s] = interp_e(t0 + 0.5f * kDT);
        e.hi[s]  = interp_e(t0 + kDT);
    }
    return e;
}

constexpr ETab ETAB = make_etab();   // literals under full unroll

} // namespace

// ---- forced VOP3P packed fp32 (explicit op_sel_hi => true per-half SIMD) ----
__device__ __forceinline__ f32x2 pk_fma(f32x2 a, f32x2 b, f32x2 c) {
    f32x2 d;
    asm("v_pk_fma_f32 %0, %1, %2, %3 op_sel:[0,0,0] op_sel_hi:[1,1,1]"
        : "=v"(d) : "v"(a), "v"(b), "v"(c));
    return d;
}
__device__ __forceinline__ f32x2 pk_add(f32x2 a, f32x2 b) {
    f32x2 d;
    asm("v_pk_add_f32 %0, %1, %2 op_sel:[0,0] op_sel_hi:[1,1]"
        : "=v"(d) : "v"(a), "v"(b));
    return d;
}
// a - b == fma(-1, b, a): exact product, single rounding — identical to v_sub.
__device__ __forceinline__ f32x2 pk_sub(f32x2 a, f32x2 b, f32x2 m1) {
    return pk_fma(m1, b, a);
}

// Single-lane, w-space chain (w_i = r*q_i):
//   specials x0,x1,x2 (scalar)
//   chain pairs W0=(w_q1,w_q5) W1=(w_q2,w_q6) W2=(w_q3,w_q7) W3=(w_q4,w_out)
//   prev(W0) = (r*x2, W3.x); chain derivs = pure packed subtracts.
//   out-feedback: k2*out = k2r * W3.y,  k2r = k2*tau/8.
struct Dv { float d0, d1, d2; f32x2 G0, G1, G2, G3; };

__global__ __launch_bounds__(256) void stats5_kernel(
    const float* __restrict__ params,
    const float* __restrict__ design,
    const float* __restrict__ noise,
    float* __restrict__ out,
    int B)
{
    int b = blockIdx.x * blockDim.x + threadIdx.x;
    if (b >= B) return;

    // ---- design readout (wave-uniform -> SGPR)
    int ij[OBS], ij1[OBS]; float wj[OBS], w1j[OBS];
    #pragma unroll
    for (int j = 0; j < OBS; j++) {
        float pos = design[j] * (1.0f / kDT);
        int i = (int)pos;
        i = i < 0 ? 0 : (i > NSTEP - 1 ? NSTEP - 1 : i);
        float w = pos - (float)i;
        ij[j]  = __builtin_amdgcn_readfirstlane(i);
        ij1[j] = ij[j] + 1;
        int wb = __builtin_amdgcn_readfirstlane(__float_as_int(w));
        wj[j]  = __int_as_float(wb);
        w1j[j] = 1.0f - wj[j];
    }

    unsigned long long m_lo = 0ull, m_hi = 0ull;
    #pragma unroll
    for (int j = 0; j < OBS; j++) {
        if (ij[j]  < 64) m_lo |= 1ull << ij[j];  else m_hi |= 1ull << (ij[j]  - 64);
        if (ij1[j] < 64) m_lo |= 1ull << ij1[j]; else m_hi |= 1ull << (ij1[j] - 64);
    }

    // ---- parameter transform
    float p0 = params[3 * b], p1 = params[3 * b + 1], p2 = params[3 * b + 2];
    const float INV_SQRT2 = 0.7071067811865476f;
    float k1  = fmaf(0.5f * erfcf(-p0 * INV_SQRT2), 2.5f,  0.5f);
    float k2  = fmaf(0.5f * erfcf(-p1 * INV_SQRT2), 0.15f, 0.05f);
    float tau = fmaf(0.5f * erfcf(-p2 * INV_SQRT2), 6.0f,  4.0f);
    float r   = 8.0f / tau;

    const float hdt  = 0.5f * kDT;
    const float c6   = kDT * (1.0f / 6.0f);
    const float k2r  = 0.125f * k2 * tau;          // k2 / r (no division)
    const f32x2 crh2 = {hdt * r, hdt * r};
    const f32x2 crf2 = {kDT * r, kDT * r};
    const f32x2 c6r2 = {c6 * r, c6 * r};
    const f32x2 two2 = {2.0f, 2.0f};
    const f32x2 m1   = {-1.0f, -1.0f};

    // ---- hoist epilogue loads: bury their latency under the integration
    long long base = (long long)b * 16;
    long long nb   = (long long)B * 16;
    const float4* nz = (const float4*)(noise + base);
    float4 n0 = nz[0], n1 = nz[1], n2 = nz[2], n3 = nz[3];

    float a12[OBS], a0[OBS], b12[OBS], b0[OBS];
    #pragma unroll
    for (int j = 0; j < OBS; j++) { a12[j] = 0.f; a0[j] = 0.f; b12[j] = 0.f; b0[j] = 0.f; }

    float x0 = 3.71f, x1 = 0.f, x2 = 0.f;
    f32x2 W0 = {0.f, 0.f}, W1 = W0, W2 = W0, W3 = W0;

    if (m_lo & 1ull) {
        #pragma unroll
        for (int j = 0; j < OBS; j++)
            if (ij[j] == 0) { a12[j] = 0.f; a0[j] = 3.71f; }
    }

    auto DERIV = [&](float k1E, float X0, float X1, float X2,
                     const f32x2& V0, const f32x2& V1, const f32x2& V2, const f32x2& V3) {
        Dv d;
        float a  = k1E * X0;
        float sq = X1 * X1;
        d.d0 = fmaf(k2r, V3.y, -a);
        d.d1 = a - sq;
        d.d2 = fmaf(-k2, X2, sq);
        f32x2 s0; s0.x = r * X2; s0.y = V3.x;
        d.G0 = pk_sub(s0, V0, m1);
        d.G1 = pk_sub(V0, V1, m1);
        d.G2 = pk_sub(V1, V2, m1);
        d.G3 = pk_sub(V2, V3, m1);
        return d;
    };

    #pragma unroll
    for (int s = 0; s < NSTEP; s++) {
        const float ea = ETAB.lo[s], eb = ETAB.mid[s], ec = ETAB.hi[s];
        float k1a = k1 * ea, k1b = k1 * eb, k1c = k1 * ec;

        float t0, t1, t2; f32x2 U0, U1, U2, U3;

        Dv d1 = DERIV(k1a, x0, x1, x2, W0, W1, W2, W3);
        t0 = fmaf(hdt, d1.d0, x0); t1 = fmaf(hdt, d1.d1, x1); t2 = fmaf(hdt, d1.d2, x2);
        U0 = pk_fma(crh2, d1.G0, W0); U1 = pk_fma(crh2, d1.G1, W1);
        U2 = pk_fma(crh2, d1.G2, W2); U3 = pk_fma(crh2, d1.G3, W3);

        Dv d2 = DERIV(k1b, t0, t1, t2, U0, U1, U2, U3);
        t0 = fmaf(hdt, d2.d0, x0); t1 = fmaf(hdt, d2.d1, x1); t2 = fmaf(hdt, d2.d2, x2);
        U0 = pk_fma(crh2, d2.G0, W0); U1 = pk_fma(crh2, d2.G1, W1);
        U2 = pk_fma(crh2, d2.G2, W2); U3 = pk_fma(crh2, d2.G3, W3);

        Dv d3 = DERIV(k1b, t0, t1, t2, U0, U1, U2, U3);
        t0 = fmaf(kDT, d3.d0, x0); t1 = fmaf(kDT, d3.d1, x1); t2 = fmaf(kDT, d3.d2, x2);
        U0 = pk_fma(crf2, d3.G0, W0); U1 = pk_fma(crf2, d3.G1, W1);
        U2 = pk_fma(crf2, d3.G2, W2); U3 = pk_fma(crf2, d3.G3, W3);

        Dv d4 = DERIV(k1c, t0, t1, t2, U0, U1, U2, U3);

        float u;
        u = fmaf(2.0f, d2.d0 + d3.d0, d1.d0 + d4.d0); x0 = fmaf(c6, u, x0);
        u = fmaf(2.0f, d2.d1 + d3.d1, d1.d1 + d4.d1); x1 = fmaf(c6, u, x1);
        u = fmaf(2.0f, d2.d2 + d3.d2, d1.d2 + d4.d2); x2 = fmaf(c6, u, x2);
        f32x2 sA, sB, v;
        sA = pk_add(d2.G0, d3.G0); sB = pk_add(d1.G0, d4.G0);
        v  = pk_fma(two2, sA, sB); W0 = pk_fma(c6r2, v, W0);
        sA = pk_add(d2.G1, d3.G1); sB = pk_add(d1.G1, d4.G1);
        v  = pk_fma(two2, sA, sB); W1 = pk_fma(c6r2, v, W1);
        sA = pk_add(d2.G2, d3.G2); sB = pk_add(d1.G2, d4.G2);
        v  = pk_fma(two2, sA, sB); W2 = pk_fma(c6r2, v, W2);
        sA = pk_add(d2.G3, d3.G3); sB = pk_add(d1.G3, d4.G3);
        v  = pk_fma(two2, sA, sB); W3 = pk_fma(c6r2, v, W3);

        const int ti = s + 1;
        unsigned long long mm = (ti < 64) ? (m_lo >> ti) : (m_hi >> (ti - 64));
        if (__builtin_expect((int)(mm & 1ull), 0)) {
            float s12 = x1 + x2;
            #pragma unroll
            for (int j = 0; j < OBS; j++) {
                if (ti == ij[j])  { a12[j] = s12; a0[j] = x0; }
                if (ti == ij1[j]) { b12[j] = s12; b0[j] = x0; }
            }
        }
    }

    float o1[OBS], o2[OBS];
    #pragma unroll
    for (int j = 0; j < OBS; j++) {
        o1[j] = 0.33f * fmaf(w1j[j], a12[j], wj[j] * b12[j]);
        o2[j] = 0.26f * fmaf(w1j[j], a0[j] + a12[j], wj[j] * (b0[j] + b12[j]));
    }

    float4* outv = (float4*)(out + base);
    float4* outn = (float4*)(out + nb + base);

    float4 v0 = make_float4(o1[0], o1[1], o1[2], o1[3]);
    float4 v1 = make_float4(o1[4], o1[5], o1[6], o1[7]);
    float4 v2 = make_float4(o2[0], o2[1], o2[2], o2[3]);
    float4 v3 = make_float4(o2[4], o2[5], o2[6], o2[7]);
    outv[0] = v0; outv[1] = v1; outv[2] = v2; outv[3] = v3;

    outn[0] = make_float4(fmaf(0.01f, n0.x, v0.x), fmaf(0.01f, n0.y, v0.y),
                          fmaf(0.01f, n0.z, v0.z), fmaf(0.01f, n0.w, v0.w));
    outn[1] = make_float4(fmaf(0.01f, n1.x, v1.x), fmaf(0.01f, n1.y, v1.y),
                          fmaf(0.01f, n1.z, v1.z), fmaf(0.01f, n1.w, v1.w));
    outn[2] = make_float4(fmaf(0.01f, n2.x, v2.x), fmaf(0.01f, n2.y, v2.y),
                          fmaf(0.01f, n2.z, v2.z), fmaf(0.01f, n2.w, v2.w));
    outn[3] = make_float4(fmaf(0.01f, n3.x, v3.x), fmaf(0.01f, n3.y, v3.y),
                          fmaf(0.01f, n3.z, v3.z), fmaf(0.01f, n3.w, v3.w));
}

extern "C" void kernel_launch(void* const* d_in, const int* in_sizes, int n_in,
                              void* d_out, int out_size, void* d_ws, size_t ws_size,
                              hipStream_t stream) {
    const float* params = (const float*)d_in[0];
    const float* design = (const float*)d_in[1];
    const float* noise  = (const float*)d_in[2];
    float* out = (float*)d_out;
    int B = in_sizes[0] / 3;
    int block = 256;
    int grid = (B + block - 1) / block;
    stats5_kernel<<<grid, block, 0, stream>>>(params, design, noise, out, B);
}